// Round 6
// baseline (2796.935 us; speedup 1.0000x reference)
//
#include <hip/hip_runtime.h>

#define N_NODES 100000
#define N_EDGES 3200000
#define N_FEAT 24
#define PADF4 8                         // padded src row = 32 floats = 128B
#define BSHIFT 8                        // 256 rows per coarse bucket
#define NBUCK ((N_NODES + 255) >> 8)    // 391 coarse buckets
#define NFINE (NBUCK * 4)               // 1564 fine buckets of 64 rows
#define EPT 16
#define TILE (256 * EPT)                // 4096 edges per partition tile
#define NTILES ((N_EDGES + TILE - 1) / TILE)
#define CAP 12288                       // LDS staging entries (96KB)
#define NKEY 1024                       // sort key: fine(2b) x colbin(8b)

// ---------------- small utils ----------------

__global__ void zero_kernel(int* __restrict__ p, int n) {
    int i = blockIdx.x * blockDim.x + threadIdx.x;
    if (i < n) p[i] = 0;
}

// ---------------- coarse bucket histogram ----------------
__global__ __launch_bounds__(256) void bhist_kernel(const int* __restrict__ row,
                                                    int* __restrict__ bcnt) {
    __shared__ int h[NBUCK];
    for (int i = threadIdx.x; i < NBUCK; i += 256) h[i] = 0;
    __syncthreads();
    int stride = gridDim.x * blockDim.x;
    for (int i = blockIdx.x * blockDim.x + threadIdx.x; i < N_EDGES; i += stride)
        atomicAdd(&h[row[i] >> BSHIFT], 1);
    __syncthreads();
    for (int i = threadIdx.x; i < NBUCK; i += 256) {
        int c = h[i];
        if (c) atomicAdd(&bcnt[i], c);
    }
}

// ---------------- coarse bucket scan ----------------
__global__ __launch_bounds__(512) void bscan_kernel(const int* __restrict__ bcnt,
                                                    int* __restrict__ bbase,
                                                    int* __restrict__ bcursor) {
    __shared__ int part[512];
    int tid = threadIdx.x;
    int v = (tid < NBUCK) ? bcnt[tid] : 0;
    part[tid] = v;
    __syncthreads();
    for (int off = 1; off < 512; off <<= 1) {
        int p = (tid >= off) ? part[tid - off] : 0;
        __syncthreads();
        part[tid] += p;
        __syncthreads();
    }
    int ex = (tid > 0) ? part[tid - 1] : 0;
    if (tid <= NBUCK) {
        bbase[tid] = ex;
        if (tid < NBUCK) bcursor[tid] = ex;
    }
}

// ---------------- level 1: partition edges into coarse bucket regions ----------------
__global__ __launch_bounds__(256) void part_kernel(const int* __restrict__ row,
                                                   const int* __restrict__ col,
                                                   const float* __restrict__ val,
                                                   int* __restrict__ bcursor,
                                                   int2* __restrict__ epk) {
    __shared__ int h[NBUCK];
    __shared__ int lstart[NBUCK];
    __shared__ int delta[NBUCK];
    __shared__ int psum[256];
    __shared__ int2 stage[TILE];
    __shared__ unsigned short bidx[TILE];
    const int tid = threadIdx.x;
    for (int i = tid; i < NBUCK; i += 256) h[i] = 0;
    __syncthreads();

    const int tbase = blockIdx.x * TILE;
    const int m = min(TILE, N_EDGES - tbase);
    const int base = tbase + tid * EPT;
    int rowj[EPT], rk[EPT];
    #pragma unroll
    for (int j = 0; j < EPT; ++j) {
        int e = base + j;
        if (e < N_EDGES) {
            int r = row[e];
            rowj[j] = r;
            rk[j] = atomicAdd(&h[r >> BSHIFT], 1);
        } else rowj[j] = -1;
    }
    __syncthreads();

    {   // exclusive scan h -> lstart
        int lo = tid * 2;
        int hi = min(NBUCK, lo + 2);
        int s = 0;
        for (int j = lo; j < hi; ++j) s += h[j];
        psum[tid] = s;
        __syncthreads();
        for (int off = 1; off < 256; off <<= 1) {
            int p = (tid >= off) ? psum[tid - off] : 0;
            __syncthreads();
            psum[tid] += p;
            __syncthreads();
        }
        int run = (tid > 0) ? psum[tid - 1] : 0;
        for (int j = lo; j < hi; ++j) {
            lstart[j] = run;
            run += h[j];
        }
    }
    __syncthreads();

    for (int i = tid; i < NBUCK; i += 256) {
        int c = h[i];
        int g = c ? atomicAdd(&bcursor[i], c) : 0;
        delta[i] = g - lstart[i];
    }
    __syncthreads();

    #pragma unroll
    for (int j = 0; j < EPT; ++j) {
        if (rowj[j] >= 0) {
            int e = base + j;
            int b = rowj[j] >> BSHIFT;
            int rl = rowj[j] & 255;
            int slot = lstart[b] + rk[j];
            int2 pk;
            pk.x = col[e] | (rl << 17);   // col < 2^17, rl < 2^8
            pk.y = __float_as_int(val[e]);
            stage[slot] = pk;
            bidx[slot] = (unsigned short)b;
        }
    }
    __syncthreads();

    for (int i = tid; i < m; i += 256) {
        int b = bidx[i];
        epk[delta[b] + i] = stage[i];
    }
}

// ---------------- level 2: sort each coarse bucket by (fine-bucket, colbin) ----------------
// key = ((rl>>6) << 8) | (col >> 9)  -> edges grouped into 64-row fine buckets,
// column-sorted (512-col bins) within each. Emits fstart[] fine boundaries.
__global__ __launch_bounds__(256) void place2_kernel(const int* __restrict__ bbase,
                                                     int2* __restrict__ epk,
                                                     int* __restrict__ fstart) {
    __shared__ int kcnt[NKEY];
    __shared__ int kstart[NKEY];
    __shared__ int kcur[NKEY];
    __shared__ int psum[256];
    __shared__ int2 stage[CAP];
    int b = blockIdx.x;
    int tid = threadIdx.x;
    int gb = bbase[b];
    int n = bbase[b + 1] - gb;
    for (int j = tid; j < NKEY; j += 256) kcnt[j] = 0;
    __syncthreads();
    for (int i = tid; i < n; i += 256) {
        int x = epk[gb + i].x;
        int key = (((x >> 23) & 3) << 8) | ((x >> 9) & 255);
        atomicAdd(&kcnt[key], 1);
    }
    __syncthreads();
    {   // scan NKEY (chunk=4 per thread)
        int lo = tid * 4, s = 0;
        #pragma unroll
        for (int j = 0; j < 4; ++j) s += kcnt[lo + j];
        psum[tid] = s;
        __syncthreads();
        for (int off = 1; off < 256; off <<= 1) {
            int p = (tid >= off) ? psum[tid - off] : 0;
            __syncthreads();
            psum[tid] += p;
            __syncthreads();
        }
        int run = (tid > 0) ? psum[tid - 1] : 0;
        #pragma unroll
        for (int j = 0; j < 4; ++j) {
            kstart[lo + j] = run;
            kcur[lo + j] = run;
            run += kcnt[lo + j];
        }
    }
    __syncthreads();
    if (tid < 4) fstart[b * 4 + tid] = gb + kstart[tid << 8];
    if (b == 0 && tid == 0) fstart[NFINE] = N_EDGES;
    for (int i = tid; i < n; i += 256) {
        int2 p = epk[gb + i];
        int key = (((p.x >> 23) & 3) << 8) | ((p.x >> 9) & 255);
        int slot = atomicAdd(&kcur[key], 1);
        if (slot < CAP) stage[slot] = p;
        else epk[gb + slot] = p;      // unreachable overflow guard
    }
    __syncthreads();
    for (int i = tid; i < n && i < CAP; i += 256) epk[gb + i] = stage[i];
}

// ---------------- pad-copy: x [N][24] -> bufA [N][32] ----------------
__global__ __launch_bounds__(256) void pad_copy_kernel(const float4* __restrict__ x4,
                                                       float4* __restrict__ dst) {
    int t = blockIdx.x * blockDim.x + threadIdx.x;
    int r = t >> 3;
    if (r >= N_NODES) return;
    int sub = t & 7;
    float4 v;
    if (sub < 6) v = x4[r * 6 + sub];
    else         v = make_float4(0.f, 0.f, 0.f, 0.f);
    dst[r * PADF4 + sub] = v;
}

// ---------------- SpMM: fine bucket per block, LDS accumulator ----------------
__device__ __forceinline__ void edge_accum(int2 p, int sub, float* acc,
                                           const float4* __restrict__ src) {
    float4 xv = src[(p.x & 0x1FFFF) * PADF4 + sub];
    if (sub < 6) {
        float v = __int_as_float(p.y);
        float* a = &acc[((p.x >> 17) & 63) * 24 + sub * 4];
        atomicAdd(a + 0, v * xv.x);
        atomicAdd(a + 1, v * xv.y);
        atomicAdd(a + 2, v * xv.z);
        atomicAdd(a + 3, v * xv.w);
    }
}

__global__ __launch_bounds__(256) void spmm_lds_kernel(const int* __restrict__ fstart,
                                                       const int2* __restrict__ epk,
                                                       const float4* __restrict__ src,
                                                       float4* __restrict__ dstp) {
    __shared__ float acc[64 * 24];
    int f = blockIdx.x;
    int tid = threadIdx.x;
    #pragma unroll
    for (int k = 0; k < 6; ++k) acc[k * 256 + tid] = 0.f;
    __syncthreads();
    int s = fstart[f];
    int e = fstart[f + 1];
    int g = tid >> 3, sub = tid & 7;
    int i = s + g;
    for (; i + 32 < e; i += 64) {       // 2-edge unroll: both gathers in flight
        int2 p0 = epk[i];
        int2 p1 = epk[i + 32];
        edge_accum(p0, sub, acc, src);
        edge_accum(p1, sub, acc, src);
    }
    if (i < e) edge_accum(epk[i], sub, acc, src);
    __syncthreads();
    float* dst = (float*)dstp;
    int base_row = f * 64;
    #pragma unroll
    for (int k = 0; k < 6; ++k) {
        int idx = k * 256 + tid;        // 0..1535
        int row = idx / 24;
        int el  = idx - row * 24;
        int r = base_row + row;
        if (r < N_NODES) dst[r * 32 + el] = acc[row * 24 + el];
    }
}

__global__ __launch_bounds__(256) void spmm_lds_final_kernel(const int* __restrict__ fstart,
                                                             const int2* __restrict__ epk,
                                                             const float4* __restrict__ src,
                                                             float* __restrict__ out) {
    __shared__ float acc[64 * 24];
    int f = blockIdx.x;
    int tid = threadIdx.x;
    #pragma unroll
    for (int k = 0; k < 6; ++k) acc[k * 256 + tid] = 0.f;
    __syncthreads();
    int s = fstart[f];
    int e = fstart[f + 1];
    int g = tid >> 3, sub = tid & 7;
    int i = s + g;
    for (; i + 32 < e; i += 64) {
        int2 p0 = epk[i];
        int2 p1 = epk[i + 32];
        edge_accum(p0, sub, acc, src);
        edge_accum(p1, sub, acc, src);
    }
    if (i < e) edge_accum(epk[i], sub, acc, src);
    __syncthreads();
    int base_row = f * 64;
    #pragma unroll
    for (int k = 0; k < 6; ++k) {
        int idx = k * 256 + tid;
        int row = idx / 24;
        int el  = idx - row * 24;
        int r = base_row + row;
        if (r < N_NODES) out[r * 24 + el] = acc[row * 24 + el];
    }
}

// ---------------- launch ----------------

extern "C" void kernel_launch(void* const* d_in, const int* in_sizes, int n_in,
                              void* d_out, int out_size, void* d_ws, size_t ws_size,
                              hipStream_t stream) {
    const float* x       = (const float*)d_in[0];
    const float* values  = (const float*)d_in[1];
    const int*   row_idx = (const int*)d_in[2];
    const int*   col_idx = (const int*)d_in[3];
    float* out = (float*)d_out;

    char* ws = (char*)d_ws;
    // workspace layout (~51.3MB, 128B-aligned)
    int*    bcnt    = (int*)(ws + 0);           // NBUCK ints
    int*    bbase   = (int*)(ws + 2048);        // NBUCK+1 ints
    int*    bcursor = (int*)(ws + 4096);        // NBUCK ints
    int*    fstart  = (int*)(ws + 6144);        // NFINE+1 ints
    int2*   epk     = (int2*)(ws + 16384);      // E * 8B = 25.6 MB
    float4* bufA    = (float4*)(ws + 25616384); // N*32 floats = 12.8 MB
    float4* bufB    = (float4*)(ws + 38416384); // N*32 floats = 12.8 MB

    zero_kernel<<<4, 256, 0, stream>>>(bcnt, NBUCK);
    bhist_kernel<<<512, 256, 0, stream>>>(row_idx, bcnt);
    bscan_kernel<<<1, 512, 0, stream>>>(bcnt, bbase, bcursor);
    part_kernel<<<NTILES, 256, 0, stream>>>(row_idx, col_idx, values, bcursor, epk);
    place2_kernel<<<NBUCK, 256, 0, stream>>>(bbase, epk, fstart);

    const int pad_blocks = (N_NODES * 8 + 255) / 256;
    pad_copy_kernel<<<pad_blocks, 256, 0, stream>>>((const float4*)x, bufA);
    spmm_lds_kernel<<<NFINE, 256, 0, stream>>>(fstart, epk, bufA, bufB);
    spmm_lds_kernel<<<NFINE, 256, 0, stream>>>(fstart, epk, bufB, bufA);
    spmm_lds_kernel<<<NFINE, 256, 0, stream>>>(fstart, epk, bufA, bufB);
    spmm_lds_kernel<<<NFINE, 256, 0, stream>>>(fstart, epk, bufB, bufA);
    spmm_lds_kernel<<<NFINE, 256, 0, stream>>>(fstart, epk, bufA, bufB);
    spmm_lds_final_kernel<<<NFINE, 256, 0, stream>>>(fstart, epk, bufB, out);
}

// Round 7
// 492.646 us; speedup vs baseline: 5.6774x; 5.6774x over previous
//
#include <hip/hip_runtime.h>

#define N_NODES 100000
#define N_EDGES 3200000
#define N_FEAT 24
#define PADF4 8                         // padded row = 32 floats = 128B
#define BSHIFT 8                        // 256 rows per bucket
#define NBUCK ((N_NODES + 255) >> 8)    // 391 buckets
#define EPT 16                          // edges per thread in partition
#define TILE (256 * EPT)                // 4096 edges per block-tile
#define NTILES ((N_EDGES + TILE - 1) / TILE)  // 782
#define CAP 9216                        // level-2 LDS staging entries (72KB)
#define DMAX 256                        // degree buckets for balance sort
#define NKEY 4096                       // (row_local 8b) x (colbin 4b)

// ---------------- small utils ----------------

__global__ void zero_kernel(int* __restrict__ p, int n) {
    int i = blockIdx.x * blockDim.x + threadIdx.x;
    if (i < n) p[i] = 0;
}

// ---------------- bucket histogram (LDS-aggregated) ----------------
__global__ __launch_bounds__(256) void bhist_kernel(const int* __restrict__ row,
                                                    int* __restrict__ bcnt) {
    __shared__ int h[NBUCK];
    for (int i = threadIdx.x; i < NBUCK; i += 256) h[i] = 0;
    __syncthreads();
    int stride = gridDim.x * blockDim.x;
    for (int i = blockIdx.x * blockDim.x + threadIdx.x; i < N_EDGES; i += stride)
        atomicAdd(&h[row[i] >> BSHIFT], 1);
    __syncthreads();
    for (int i = threadIdx.x; i < NBUCK; i += 256) {
        int c = h[i];
        if (c) atomicAdd(&bcnt[i], c);
    }
}

// ---------------- bucket exclusive scan -> bbase[0..NBUCK], bcursor ----------------
__global__ __launch_bounds__(512) void bscan_kernel(const int* __restrict__ bcnt,
                                                    int* __restrict__ bbase,
                                                    int* __restrict__ bcursor) {
    __shared__ int part[512];
    int tid = threadIdx.x;
    int v = (tid < NBUCK) ? bcnt[tid] : 0;
    part[tid] = v;
    __syncthreads();
    for (int off = 1; off < 512; off <<= 1) {
        int p = (tid >= off) ? part[tid - off] : 0;
        __syncthreads();
        part[tid] += p;
        __syncthreads();
    }
    int ex = (tid > 0) ? part[tid - 1] : 0;
    if (tid <= NBUCK) {
        bbase[tid] = ex;              // bbase[NBUCK] == N_EDGES
        if (tid < NBUCK) bcursor[tid] = ex;
    }
}

// ---------------- level 1: partition edges into bucket regions ----------------
__global__ __launch_bounds__(256) void part_kernel(const int* __restrict__ row,
                                                   const int* __restrict__ col,
                                                   const float* __restrict__ val,
                                                   int* __restrict__ bcursor,
                                                   int2* __restrict__ epk) {
    __shared__ int h[NBUCK];
    __shared__ int lstart[NBUCK];
    __shared__ int delta[NBUCK];      // gpos[b] - lstart[b]
    __shared__ int psum[256];
    __shared__ int2 stage[TILE];
    __shared__ unsigned short bidx[TILE];
    const int tid = threadIdx.x;
    for (int i = tid; i < NBUCK; i += 256) h[i] = 0;
    __syncthreads();

    const int tbase = blockIdx.x * TILE;
    const int m = min(TILE, N_EDGES - tbase);
    const int base = tbase + tid * EPT;
    int rowj[EPT], rk[EPT];
    #pragma unroll
    for (int j = 0; j < EPT; ++j) {
        int e = base + j;
        if (e < N_EDGES) {
            int r = row[e];
            rowj[j] = r;
            rk[j] = atomicAdd(&h[r >> BSHIFT], 1);
        } else rowj[j] = -1;
    }
    __syncthreads();

    {   // exclusive scan h -> lstart
        int lo = tid * 2;
        int hi = min(NBUCK, lo + 2);
        int s = 0;
        for (int j = lo; j < hi; ++j) s += h[j];
        psum[tid] = s;
        __syncthreads();
        for (int off = 1; off < 256; off <<= 1) {
            int p = (tid >= off) ? psum[tid - off] : 0;
            __syncthreads();
            psum[tid] += p;
            __syncthreads();
        }
        int run = (tid > 0) ? psum[tid - 1] : 0;
        for (int j = lo; j < hi; ++j) {
            lstart[j] = run;
            run += h[j];
        }
    }
    __syncthreads();

    // reserve global chunks (one atomic per (block,bucket))
    for (int i = tid; i < NBUCK; i += 256) {
        int c = h[i];
        int g = c ? atomicAdd(&bcursor[i], c) : 0;
        delta[i] = g - lstart[i];
    }
    __syncthreads();

    #pragma unroll
    for (int j = 0; j < EPT; ++j) {
        if (rowj[j] >= 0) {
            int e = base + j;
            int b = rowj[j] >> BSHIFT;
            int rl = rowj[j] & 255;
            int slot = lstart[b] + rk[j];
            int2 pk;
            pk.x = col[e] | (rl << 17);   // col < 2^17, rl < 2^8
            pk.y = __float_as_int(val[e]);
            stage[slot] = pk;
            bidx[slot] = (unsigned short)b;
        }
    }
    __syncthreads();

    for (int i = tid; i < m; i += 256) {
        int b = bidx[i];
        epk[delta[b] + i] = stage[i];
    }
}

// ---------------- level 2: CSR placement, column-sorted within each row ----------------
// key = (row_local << 4) | (col >> 13): edges land in row-major CSR order with
// 8K-column bins ascending inside each row -> chip-wide column sweep in SpMM.
// Emits starts[] and the degree histogram (degree = chunk sum of the scan).
__global__ __launch_bounds__(256) void place_kernel(const int* __restrict__ bbase,
                                                    int2* __restrict__ epk,
                                                    int* __restrict__ starts,
                                                    int* __restrict__ dcnt) {
    __shared__ int kcnt[NKEY];       // 16 KB
    __shared__ int kstart[NKEY];     // 16 KB
    __shared__ int kcur[NKEY];       // 16 KB
    __shared__ int psum[256];
    __shared__ int dh[DMAX];
    __shared__ int2 stage[CAP];      // 72 KB
    int b = blockIdx.x;
    int tid = threadIdx.x;
    int gb = bbase[b];
    int n = bbase[b + 1] - gb;
    for (int j = tid; j < NKEY; j += 256) kcnt[j] = 0;
    dh[tid] = 0;
    __syncthreads();
    for (int i = tid; i < n; i += 256) {
        int x = epk[gb + i].x;
        int key = (((x >> 17) & 255) << 4) | ((x >> 13) & 15);
        atomicAdd(&kcnt[key], 1);
    }
    __syncthreads();
    // chunk=16 scan: thread tid owns exactly row tid's 16 bins
    int lo = tid << 4;
    int deg = 0;
    #pragma unroll
    for (int j = 0; j < 16; ++j) deg += kcnt[lo + j];
    int r_glob = (b << BSHIFT) + tid;
    if (r_glob < N_NODES) atomicAdd(&dh[min(deg, DMAX - 1)], 1);
    psum[tid] = deg;
    __syncthreads();
    for (int off = 1; off < 256; off <<= 1) {
        int p = (tid >= off) ? psum[tid - off] : 0;
        __syncthreads();
        psum[tid] += p;
        __syncthreads();
    }
    int run = (tid > 0) ? psum[tid - 1] : 0;
    if (r_glob < N_NODES) starts[r_glob] = gb + run;
    if (b == 0 && tid == 0) starts[N_NODES] = N_EDGES;
    #pragma unroll
    for (int j = 0; j < 16; ++j) {
        kstart[lo + j] = run;
        kcur[lo + j] = run;
        run += kcnt[lo + j];
    }
    __syncthreads();
    {   // flush degree histogram
        int c = dh[tid];
        if (c) atomicAdd(&dcnt[tid], c);
    }
    for (int i = tid; i < n; i += 256) {
        int2 p = epk[gb + i];
        int key = (((p.x >> 17) & 255) << 4) | ((p.x >> 13) & 15);
        int slot = atomicAdd(&kcur[key], 1);
        int2 fin;
        fin.x = p.x & 0x1FFFF;       // strip row_local
        fin.y = p.y;
        if (slot < CAP) stage[slot] = fin;
        else epk[gb + slot] = fin;   // overflow guard (statistically unreachable)
    }
    __syncthreads();
    for (int i = tid; i < n && i < CAP; i += 256) epk[gb + i] = stage[i];
}

// ---------------- degree scan + LDS-aggregated counting-sort scatter ----------------
__global__ __launch_bounds__(256) void dscan_kernel(const int* __restrict__ dcnt,
                                                    int* __restrict__ dcur) {
    __shared__ int part[DMAX];
    int tid = threadIdx.x;
    int v = dcnt[tid];
    part[tid] = v;
    __syncthreads();
    for (int off = 1; off < DMAX; off <<= 1) {
        int p = (tid >= off) ? part[tid - off] : 0;
        __syncthreads();
        part[tid] += p;
        __syncthreads();
    }
    dcur[tid] = part[tid] - v;   // exclusive
}

__global__ __launch_bounds__(256) void dscatter_kernel(const int* __restrict__ starts,
                                                       int* __restrict__ dcur,
                                                       int* __restrict__ perm) {
    __shared__ int h[DMAX];
    __shared__ int chunk[DMAX];
    int tid = threadIdx.x;
    int r = blockIdx.x * 256 + tid;
    h[tid] = 0;
    __syncthreads();
    int d = -1, rk = 0;
    if (r < N_NODES) {
        d = min(starts[r + 1] - starts[r], DMAX - 1);
        rk = atomicAdd(&h[d], 1);
    }
    __syncthreads();
    int c = h[tid];
    chunk[tid] = c ? atomicAdd(&dcur[tid], c) : 0;   // one atomic per (block,deg)
    __syncthreads();
    if (r < N_NODES) perm[chunk[d] + rk] = r;
}

// ---------------- pad-copy: x [N][24] -> bufA [N][32] ----------------
__global__ __launch_bounds__(256) void pad_copy_kernel(const float4* __restrict__ x4,
                                                       float4* __restrict__ dst) {
    int t = blockIdx.x * blockDim.x + threadIdx.x;
    int r = t >> 3;
    if (r >= N_NODES) return;
    int sub = t & 7;
    float4 v;
    if (sub < 6) v = x4[r * 6 + sub];
    else         v = make_float4(0.f, 0.f, 0.f, 0.f);
    dst[r * PADF4 + sub] = v;
}

// ---------------- SpMM on padded buffers (register accum, degree-grouped) ----------------
__global__ __launch_bounds__(256) void spmm_pad_kernel(const int* __restrict__ starts,
                                                       const int* __restrict__ perm,
                                                       const int2* __restrict__ epk,
                                                       const float4* __restrict__ src,
                                                       float4* __restrict__ dst) {
    int t = blockIdx.x * blockDim.x + threadIdx.x;
    int g = t >> 3;
    if (g >= N_NODES) return;
    int rowi = perm[g];
    int sub = t & 7;
    int s = starts[rowi];
    int e = starts[rowi + 1];
    float4 acc = make_float4(0.f, 0.f, 0.f, 0.f);
    for (int i = s; i < e; ++i) {
        int2 pk = epk[i];
        float v = __int_as_float(pk.y);
        float4 xv = src[pk.x * PADF4 + sub];
        acc.x = fmaf(v, xv.x, acc.x);
        acc.y = fmaf(v, xv.y, acc.y);
        acc.z = fmaf(v, xv.z, acc.z);
        acc.w = fmaf(v, xv.w, acc.w);
    }
    dst[rowi * PADF4 + sub] = acc;
}

__global__ __launch_bounds__(256) void spmm_final_kernel(const int* __restrict__ starts,
                                                         const int* __restrict__ perm,
                                                         const int2* __restrict__ epk,
                                                         const float4* __restrict__ src,
                                                         float* __restrict__ out) {
    int t = blockIdx.x * blockDim.x + threadIdx.x;
    int g = t >> 3;
    if (g >= N_NODES) return;
    int rowi = perm[g];
    int sub = t & 7;
    int s = starts[rowi];
    int e = starts[rowi + 1];
    float4 acc = make_float4(0.f, 0.f, 0.f, 0.f);
    for (int i = s; i < e; ++i) {
        int2 pk = epk[i];
        float v = __int_as_float(pk.y);
        float4 xv = src[pk.x * PADF4 + sub];
        acc.x = fmaf(v, xv.x, acc.x);
        acc.y = fmaf(v, xv.y, acc.y);
        acc.z = fmaf(v, xv.z, acc.z);
        acc.w = fmaf(v, xv.w, acc.w);
    }
    if (sub < 6) *(float4*)(out + rowi * N_FEAT + sub * 4) = acc;
}

// ---------------- launch ----------------

extern "C" void kernel_launch(void* const* d_in, const int* in_sizes, int n_in,
                              void* d_out, int out_size, void* d_ws, size_t ws_size,
                              hipStream_t stream) {
    const float* x       = (const float*)d_in[0];
    const float* values  = (const float*)d_in[1];
    const int*   row_idx = (const int*)d_in[2];
    const int*   col_idx = (const int*)d_in[3];
    float* out = (float*)d_out;

    char* ws = (char*)d_ws;
    // workspace layout (~52MB, 128B-aligned offsets)
    int*    bcnt    = (int*)(ws + 0);          // NBUCK ints
    int*    bbase   = (int*)(ws + 2048);       // NBUCK+1 ints
    int*    bcursor = (int*)(ws + 4096);       // NBUCK ints
    int*    dcnt    = (int*)(ws + 6144);       // DMAX ints
    int*    dcur    = (int*)(ws + 7168);       // DMAX ints
    int*    starts  = (int*)(ws + 8192);       // N_NODES+1 ints
    int*    perm    = (int*)(ws + 408576);     // N_NODES ints
    int2*   epk     = (int2*)(ws + 808576);    // E * 8B = 25.6 MB
    float4* bufA    = (float4*)(ws + 26408576);// N*32 floats = 12.8 MB
    float4* bufB    = (float4*)(ws + 39208576);// N*32 floats = 12.8 MB

    zero_kernel<<<4, 256, 0, stream>>>(bcnt, NBUCK);
    zero_kernel<<<1, 256, 0, stream>>>(dcnt, DMAX);
    bhist_kernel<<<512, 256, 0, stream>>>(row_idx, bcnt);
    bscan_kernel<<<1, 512, 0, stream>>>(bcnt, bbase, bcursor);
    part_kernel<<<NTILES, 256, 0, stream>>>(row_idx, col_idx, values, bcursor, epk);
    place_kernel<<<NBUCK, 256, 0, stream>>>(bbase, epk, starts, dcnt);

    const int node_blocks = (N_NODES + 255) / 256;
    dscan_kernel<<<1, DMAX, 0, stream>>>(dcnt, dcur);
    dscatter_kernel<<<node_blocks, 256, 0, stream>>>(starts, dcur, perm);

    const int spmm_blocks = (N_NODES * 8 + 255) / 256;
    pad_copy_kernel<<<spmm_blocks, 256, 0, stream>>>((const float4*)x, bufA);
    spmm_pad_kernel<<<spmm_blocks, 256, 0, stream>>>(starts, perm, epk, bufA, bufB);
    spmm_pad_kernel<<<spmm_blocks, 256, 0, stream>>>(starts, perm, epk, bufB, bufA);
    spmm_pad_kernel<<<spmm_blocks, 256, 0, stream>>>(starts, perm, epk, bufA, bufB);
    spmm_pad_kernel<<<spmm_blocks, 256, 0, stream>>>(starts, perm, epk, bufB, bufA);
    spmm_pad_kernel<<<spmm_blocks, 256, 0, stream>>>(starts, perm, epk, bufA, bufB);
    spmm_final_kernel<<<spmm_blocks, 256, 0, stream>>>(starts, perm, epk, bufB, out);
}

// Round 8
// 482.657 us; speedup vs baseline: 5.7949x; 1.0207x over previous
//
#include <hip/hip_runtime.h>

#define N_NODES 100000
#define N_EDGES 3200000
#define N_FEAT 24
#define PADF4 8                         // padded row = 32 floats = 128B
#define BSHIFT 8                        // 256 rows per bucket
#define NBUCK ((N_NODES + 255) >> 8)    // 391 buckets
#define EPT 16                          // edges per thread in partition
#define TILE (256 * EPT)                // 4096 edges per block-tile
#define NTILES ((N_EDGES + TILE - 1) / TILE)  // 782
#define CAP 9216                        // level-2 LDS staging entries (72KB)
#define DMAX 256                        // degree buckets for balance sort
#define NKEY 4096                       // (row_local 8b) x (colbin 4b)

// ---------------- small utils ----------------

__global__ void zero_kernel(int* __restrict__ p, int n) {
    int i = blockIdx.x * blockDim.x + threadIdx.x;
    if (i < n) p[i] = 0;
}

// ---------------- bucket histogram (LDS-aggregated) ----------------
__global__ __launch_bounds__(256) void bhist_kernel(const int* __restrict__ row,
                                                    int* __restrict__ bcnt) {
    __shared__ int h[NBUCK];
    for (int i = threadIdx.x; i < NBUCK; i += 256) h[i] = 0;
    __syncthreads();
    int stride = gridDim.x * blockDim.x;
    for (int i = blockIdx.x * blockDim.x + threadIdx.x; i < N_EDGES; i += stride)
        atomicAdd(&h[row[i] >> BSHIFT], 1);
    __syncthreads();
    for (int i = threadIdx.x; i < NBUCK; i += 256) {
        int c = h[i];
        if (c) atomicAdd(&bcnt[i], c);
    }
}

// ---------------- bucket exclusive scan -> bbase[0..NBUCK], bcursor ----------------
__global__ __launch_bounds__(512) void bscan_kernel(const int* __restrict__ bcnt,
                                                    int* __restrict__ bbase,
                                                    int* __restrict__ bcursor) {
    __shared__ int part[512];
    int tid = threadIdx.x;
    int v = (tid < NBUCK) ? bcnt[tid] : 0;
    part[tid] = v;
    __syncthreads();
    for (int off = 1; off < 512; off <<= 1) {
        int p = (tid >= off) ? part[tid - off] : 0;
        __syncthreads();
        part[tid] += p;
        __syncthreads();
    }
    int ex = (tid > 0) ? part[tid - 1] : 0;
    if (tid <= NBUCK) {
        bbase[tid] = ex;              // bbase[NBUCK] == N_EDGES
        if (tid < NBUCK) bcursor[tid] = ex;
    }
}

// ---------------- level 1: partition edges into bucket regions ----------------
__global__ __launch_bounds__(256) void part_kernel(const int* __restrict__ row,
                                                   const int* __restrict__ col,
                                                   const float* __restrict__ val,
                                                   int* __restrict__ bcursor,
                                                   int2* __restrict__ epk) {
    __shared__ int h[NBUCK];
    __shared__ int lstart[NBUCK];
    __shared__ int delta[NBUCK];      // gpos[b] - lstart[b]
    __shared__ int psum[256];
    __shared__ int2 stage[TILE];
    __shared__ unsigned short bidx[TILE];
    const int tid = threadIdx.x;
    for (int i = tid; i < NBUCK; i += 256) h[i] = 0;
    __syncthreads();

    const int tbase = blockIdx.x * TILE;
    const int m = min(TILE, N_EDGES - tbase);
    const int base = tbase + tid * EPT;
    int rowj[EPT], rk[EPT];
    #pragma unroll
    for (int j = 0; j < EPT; ++j) {
        int e = base + j;
        if (e < N_EDGES) {
            int r = row[e];
            rowj[j] = r;
            rk[j] = atomicAdd(&h[r >> BSHIFT], 1);
        } else rowj[j] = -1;
    }
    __syncthreads();

    {   // exclusive scan h -> lstart
        int lo = tid * 2;
        int hi = min(NBUCK, lo + 2);
        int s = 0;
        for (int j = lo; j < hi; ++j) s += h[j];
        psum[tid] = s;
        __syncthreads();
        for (int off = 1; off < 256; off <<= 1) {
            int p = (tid >= off) ? psum[tid - off] : 0;
            __syncthreads();
            psum[tid] += p;
            __syncthreads();
        }
        int run = (tid > 0) ? psum[tid - 1] : 0;
        for (int j = lo; j < hi; ++j) {
            lstart[j] = run;
            run += h[j];
        }
    }
    __syncthreads();

    // reserve global chunks (one atomic per (block,bucket))
    for (int i = tid; i < NBUCK; i += 256) {
        int c = h[i];
        int g = c ? atomicAdd(&bcursor[i], c) : 0;
        delta[i] = g - lstart[i];
    }
    __syncthreads();

    #pragma unroll
    for (int j = 0; j < EPT; ++j) {
        if (rowj[j] >= 0) {
            int e = base + j;
            int b = rowj[j] >> BSHIFT;
            int rl = rowj[j] & 255;
            int slot = lstart[b] + rk[j];
            int2 pk;
            pk.x = col[e] | (rl << 17);   // col < 2^17, rl < 2^8
            pk.y = __float_as_int(val[e]);
            stage[slot] = pk;
            bidx[slot] = (unsigned short)b;
        }
    }
    __syncthreads();

    for (int i = tid; i < m; i += 256) {
        int b = bidx[i];
        epk[delta[b] + i] = stage[i];
    }
}

// ---------------- level 2: CSR placement, column-sorted within each row ----------------
__global__ __launch_bounds__(256) void place_kernel(const int* __restrict__ bbase,
                                                    int2* __restrict__ epk,
                                                    int* __restrict__ starts,
                                                    int* __restrict__ dcnt) {
    __shared__ int kcnt[NKEY];       // 16 KB
    __shared__ int kstart[NKEY];     // 16 KB
    __shared__ int kcur[NKEY];       // 16 KB
    __shared__ int psum[256];
    __shared__ int dh[DMAX];
    __shared__ int2 stage[CAP];      // 72 KB
    int b = blockIdx.x;
    int tid = threadIdx.x;
    int gb = bbase[b];
    int n = bbase[b + 1] - gb;
    for (int j = tid; j < NKEY; j += 256) kcnt[j] = 0;
    dh[tid] = 0;
    __syncthreads();
    for (int i = tid; i < n; i += 256) {
        int x = epk[gb + i].x;
        int key = (((x >> 17) & 255) << 4) | ((x >> 13) & 15);
        atomicAdd(&kcnt[key], 1);
    }
    __syncthreads();
    // chunk=16 scan: thread tid owns exactly row tid's 16 bins
    int lo = tid << 4;
    int deg = 0;
    #pragma unroll
    for (int j = 0; j < 16; ++j) deg += kcnt[lo + j];
    int r_glob = (b << BSHIFT) + tid;
    if (r_glob < N_NODES) atomicAdd(&dh[min(deg, DMAX - 1)], 1);
    psum[tid] = deg;
    __syncthreads();
    for (int off = 1; off < 256; off <<= 1) {
        int p = (tid >= off) ? psum[tid - off] : 0;
        __syncthreads();
        psum[tid] += p;
        __syncthreads();
    }
    int run = (tid > 0) ? psum[tid - 1] : 0;
    if (r_glob < N_NODES) starts[r_glob] = gb + run;
    if (b == 0 && tid == 0) starts[N_NODES] = N_EDGES;
    #pragma unroll
    for (int j = 0; j < 16; ++j) {
        kstart[lo + j] = run;
        kcur[lo + j] = run;
        run += kcnt[lo + j];
    }
    __syncthreads();
    {   // flush degree histogram
        int c = dh[tid];
        if (c) atomicAdd(&dcnt[tid], c);
    }
    for (int i = tid; i < n; i += 256) {
        int2 p = epk[gb + i];
        int key = (((p.x >> 17) & 255) << 4) | ((p.x >> 13) & 15);
        int slot = atomicAdd(&kcur[key], 1);
        int2 fin;
        fin.x = p.x & 0x1FFFF;       // strip row_local
        fin.y = p.y;
        if (slot < CAP) stage[slot] = fin;
        else epk[gb + slot] = fin;   // overflow guard (statistically unreachable)
    }
    __syncthreads();
    for (int i = tid; i < n && i < CAP; i += 256) epk[gb + i] = stage[i];
}

// ---------------- degree scan + LDS-aggregated counting-sort scatter ----------------
__global__ __launch_bounds__(256) void dscan_kernel(const int* __restrict__ dcnt,
                                                    int* __restrict__ dcur) {
    __shared__ int part[DMAX];
    int tid = threadIdx.x;
    int v = dcnt[tid];
    part[tid] = v;
    __syncthreads();
    for (int off = 1; off < DMAX; off <<= 1) {
        int p = (tid >= off) ? part[tid - off] : 0;
        __syncthreads();
        part[tid] += p;
        __syncthreads();
    }
    dcur[tid] = part[tid] - v;   // exclusive
}

__global__ __launch_bounds__(256) void dscatter_kernel(const int* __restrict__ starts,
                                                       int* __restrict__ dcur,
                                                       int* __restrict__ perm) {
    __shared__ int h[DMAX];
    __shared__ int chunk[DMAX];
    int tid = threadIdx.x;
    int r = blockIdx.x * 256 + tid;
    h[tid] = 0;
    __syncthreads();
    int d = -1, rk = 0;
    if (r < N_NODES) {
        d = min(starts[r + 1] - starts[r], DMAX - 1);
        rk = atomicAdd(&h[d], 1);
    }
    __syncthreads();
    int c = h[tid];
    chunk[tid] = c ? atomicAdd(&dcur[tid], c) : 0;   // one atomic per (block,deg)
    __syncthreads();
    if (r < N_NODES) perm[chunk[d] + rk] = r;
}

// ---------------- pad-copy: x [N][24] -> bufA [N][32] ----------------
__global__ __launch_bounds__(256) void pad_copy_kernel(const float4* __restrict__ x4,
                                                       float4* __restrict__ dst) {
    int t = blockIdx.x * blockDim.x + threadIdx.x;
    int r = t >> 3;
    if (r >= N_NODES) return;
    int sub = t & 7;
    float4 v;
    if (sub < 6) v = x4[r * 6 + sub];
    else         v = make_float4(0.f, 0.f, 0.f, 0.f);
    dst[r * PADF4 + sub] = v;
}

// ---------------- SpMM: 4 lanes/row, 2 float4/lane, 2-edge unroll ----------------
// 4 independent 16B gathers in flight per thread; 400K threads = 24.4 waves/CU
// -> whole grid resident in one generation.
#define EDGE_FMA8(v, x0, x1, a0, a1)                       \
    a0.x = fmaf(v, x0.x, a0.x); a0.y = fmaf(v, x0.y, a0.y); \
    a0.z = fmaf(v, x0.z, a0.z); a0.w = fmaf(v, x0.w, a0.w); \
    a1.x = fmaf(v, x1.x, a1.x); a1.y = fmaf(v, x1.y, a1.y); \
    a1.z = fmaf(v, x1.z, a1.z); a1.w = fmaf(v, x1.w, a1.w);

__global__ __launch_bounds__(256) void spmm_pad_kernel(const int* __restrict__ starts,
                                                       const int* __restrict__ perm,
                                                       const int2* __restrict__ epk,
                                                       const float4* __restrict__ src,
                                                       float4* __restrict__ dst) {
    int t = blockIdx.x * blockDim.x + threadIdx.x;
    int g = t >> 2;
    if (g >= N_NODES) return;
    int rowi = perm[g];
    int sub = t & 3;
    int s = starts[rowi];
    int e = starts[rowi + 1];
    const float4* sp = src + sub * 2;
    float4 a0 = make_float4(0.f, 0.f, 0.f, 0.f);
    float4 a1 = make_float4(0.f, 0.f, 0.f, 0.f);
    int i = s;
    for (; i + 1 < e; i += 2) {
        int2 p0 = epk[i];
        int2 p1 = epk[i + 1];
        const float4* b0 = sp + p0.x * PADF4;
        const float4* b1 = sp + p1.x * PADF4;
        float4 x00 = b0[0], x01 = b0[1];
        float4 x10 = b1[0], x11 = b1[1];
        float v0 = __int_as_float(p0.y);
        float v1 = __int_as_float(p1.y);
        EDGE_FMA8(v0, x00, x01, a0, a1);
        EDGE_FMA8(v1, x10, x11, a0, a1);
    }
    if (i < e) {
        int2 p = epk[i];
        const float4* b = sp + p.x * PADF4;
        float4 x0 = b[0], x1 = b[1];
        float v = __int_as_float(p.y);
        EDGE_FMA8(v, x0, x1, a0, a1);
    }
    float4* dp = dst + rowi * PADF4 + sub * 2;
    dp[0] = a0;
    dp[1] = a1;
}

__global__ __launch_bounds__(256) void spmm_final_kernel(const int* __restrict__ starts,
                                                         const int* __restrict__ perm,
                                                         const int2* __restrict__ epk,
                                                         const float4* __restrict__ src,
                                                         float* __restrict__ out) {
    int t = blockIdx.x * blockDim.x + threadIdx.x;
    int g = t >> 2;
    if (g >= N_NODES) return;
    int rowi = perm[g];
    int sub = t & 3;
    int s = starts[rowi];
    int e = starts[rowi + 1];
    const float4* sp = src + sub * 2;
    float4 a0 = make_float4(0.f, 0.f, 0.f, 0.f);
    float4 a1 = make_float4(0.f, 0.f, 0.f, 0.f);
    int i = s;
    for (; i + 1 < e; i += 2) {
        int2 p0 = epk[i];
        int2 p1 = epk[i + 1];
        const float4* b0 = sp + p0.x * PADF4;
        const float4* b1 = sp + p1.x * PADF4;
        float4 x00 = b0[0], x01 = b0[1];
        float4 x10 = b1[0], x11 = b1[1];
        float v0 = __int_as_float(p0.y);
        float v1 = __int_as_float(p1.y);
        EDGE_FMA8(v0, x00, x01, a0, a1);
        EDGE_FMA8(v1, x10, x11, a0, a1);
    }
    if (i < e) {
        int2 p = epk[i];
        const float4* b = sp + p.x * PADF4;
        float4 x0 = b[0], x1 = b[1];
        float v = __int_as_float(p.y);
        EDGE_FMA8(v, x0, x1, a0, a1);
    }
    if (sub < 3) {
        float4* op = (float4*)(out + rowi * N_FEAT) + sub * 2;
        op[0] = a0;
        op[1] = a1;
    }
}

// ---------------- launch ----------------

extern "C" void kernel_launch(void* const* d_in, const int* in_sizes, int n_in,
                              void* d_out, int out_size, void* d_ws, size_t ws_size,
                              hipStream_t stream) {
    const float* x       = (const float*)d_in[0];
    const float* values  = (const float*)d_in[1];
    const int*   row_idx = (const int*)d_in[2];
    const int*   col_idx = (const int*)d_in[3];
    float* out = (float*)d_out;

    char* ws = (char*)d_ws;
    // workspace layout (~52MB, 128B-aligned offsets)
    int*    bcnt    = (int*)(ws + 0);          // NBUCK ints
    int*    bbase   = (int*)(ws + 2048);       // NBUCK+1 ints
    int*    bcursor = (int*)(ws + 4096);       // NBUCK ints
    int*    dcnt    = (int*)(ws + 6144);       // DMAX ints
    int*    dcur    = (int*)(ws + 7168);       // DMAX ints
    int*    starts  = (int*)(ws + 8192);       // N_NODES+1 ints
    int*    perm    = (int*)(ws + 408576);     // N_NODES ints
    int2*   epk     = (int2*)(ws + 808576);    // E * 8B = 25.6 MB
    float4* bufA    = (float4*)(ws + 26408576);// N*32 floats = 12.8 MB
    float4* bufB    = (float4*)(ws + 39208576);// N*32 floats = 12.8 MB

    zero_kernel<<<4, 256, 0, stream>>>(bcnt, NBUCK);
    zero_kernel<<<1, 256, 0, stream>>>(dcnt, DMAX);
    bhist_kernel<<<512, 256, 0, stream>>>(row_idx, bcnt);
    bscan_kernel<<<1, 512, 0, stream>>>(bcnt, bbase, bcursor);
    part_kernel<<<NTILES, 256, 0, stream>>>(row_idx, col_idx, values, bcursor, epk);
    place_kernel<<<NBUCK, 256, 0, stream>>>(bbase, epk, starts, dcnt);

    const int node_blocks = (N_NODES + 255) / 256;
    dscan_kernel<<<1, DMAX, 0, stream>>>(dcnt, dcur);
    dscatter_kernel<<<node_blocks, 256, 0, stream>>>(starts, dcur, perm);

    const int pad_blocks = (N_NODES * 8 + 255) / 256;
    const int spmm_blocks = (N_NODES * 4 + 255) / 256;
    pad_copy_kernel<<<pad_blocks, 256, 0, stream>>>((const float4*)x, bufA);
    spmm_pad_kernel<<<spmm_blocks, 256, 0, stream>>>(starts, perm, epk, bufA, bufB);
    spmm_pad_kernel<<<spmm_blocks, 256, 0, stream>>>(starts, perm, epk, bufB, bufA);
    spmm_pad_kernel<<<spmm_blocks, 256, 0, stream>>>(starts, perm, epk, bufA, bufB);
    spmm_pad_kernel<<<spmm_blocks, 256, 0, stream>>>(starts, perm, epk, bufB, bufA);
    spmm_pad_kernel<<<spmm_blocks, 256, 0, stream>>>(starts, perm, epk, bufA, bufB);
    spmm_final_kernel<<<spmm_blocks, 256, 0, stream>>>(starts, perm, epk, bufB, out);
}

// Round 9
// 460.402 us; speedup vs baseline: 6.0750x; 1.0483x over previous
//
#include <hip/hip_runtime.h>

#define N_NODES 100000
#define N_EDGES 3200000
#define N_FEAT 24
#define PADF4 8                         // padded row = 32 floats = 128B
#define BSHIFT 8                        // 256 rows per bucket
#define NBUCK ((N_NODES + 255) >> 8)    // 391 buckets
#define EPT 16                          // edges per thread in partition
#define TILE (256 * EPT)                // 4096 edges per block-tile
#define NTILES ((N_EDGES + TILE - 1) / TILE)  // 782
#define CAP 9216                        // level-2 LDS staging entries (72KB)
#define DMAX 256                        // degree buckets for balance sort
#define NKEY 4096                       // (row_local 8b) x (colbin 4b)

// ---------------- small utils ----------------

__global__ void zero_kernel(int* __restrict__ p, int n) {
    int i = blockIdx.x * blockDim.x + threadIdx.x;
    if (i < n) p[i] = 0;
}

// ---------------- bucket histogram (LDS-aggregated) ----------------
__global__ __launch_bounds__(256) void bhist_kernel(const int* __restrict__ row,
                                                    int* __restrict__ bcnt) {
    __shared__ int h[NBUCK];
    for (int i = threadIdx.x; i < NBUCK; i += 256) h[i] = 0;
    __syncthreads();
    int stride = gridDim.x * blockDim.x;
    for (int i = blockIdx.x * blockDim.x + threadIdx.x; i < N_EDGES; i += stride)
        atomicAdd(&h[row[i] >> BSHIFT], 1);
    __syncthreads();
    for (int i = threadIdx.x; i < NBUCK; i += 256) {
        int c = h[i];
        if (c) atomicAdd(&bcnt[i], c);
    }
}

// ---------------- bucket exclusive scan -> bbase[0..NBUCK], bcursor ----------------
__global__ __launch_bounds__(512) void bscan_kernel(const int* __restrict__ bcnt,
                                                    int* __restrict__ bbase,
                                                    int* __restrict__ bcursor) {
    __shared__ int part[512];
    int tid = threadIdx.x;
    int v = (tid < NBUCK) ? bcnt[tid] : 0;
    part[tid] = v;
    __syncthreads();
    for (int off = 1; off < 512; off <<= 1) {
        int p = (tid >= off) ? part[tid - off] : 0;
        __syncthreads();
        part[tid] += p;
        __syncthreads();
    }
    int ex = (tid > 0) ? part[tid - 1] : 0;
    if (tid <= NBUCK) {
        bbase[tid] = ex;              // bbase[NBUCK] == N_EDGES
        if (tid < NBUCK) bcursor[tid] = ex;
    }
}

// ---------------- level 1: partition edges into bucket regions ----------------
__global__ __launch_bounds__(256) void part_kernel(const int* __restrict__ row,
                                                   const int* __restrict__ col,
                                                   const float* __restrict__ val,
                                                   int* __restrict__ bcursor,
                                                   int2* __restrict__ epk) {
    __shared__ int h[NBUCK];
    __shared__ int lstart[NBUCK];
    __shared__ int delta[NBUCK];      // gpos[b] - lstart[b]
    __shared__ int psum[256];
    __shared__ int2 stage[TILE];
    __shared__ unsigned short bidx[TILE];
    const int tid = threadIdx.x;
    for (int i = tid; i < NBUCK; i += 256) h[i] = 0;
    __syncthreads();

    const int tbase = blockIdx.x * TILE;
    const int m = min(TILE, N_EDGES - tbase);
    const int base = tbase + tid * EPT;
    int rowj[EPT], rk[EPT];
    #pragma unroll
    for (int j = 0; j < EPT; ++j) {
        int e = base + j;
        if (e < N_EDGES) {
            int r = row[e];
            rowj[j] = r;
            rk[j] = atomicAdd(&h[r >> BSHIFT], 1);
        } else rowj[j] = -1;
    }
    __syncthreads();

    {   // exclusive scan h -> lstart
        int lo = tid * 2;
        int hi = min(NBUCK, lo + 2);
        int s = 0;
        for (int j = lo; j < hi; ++j) s += h[j];
        psum[tid] = s;
        __syncthreads();
        for (int off = 1; off < 256; off <<= 1) {
            int p = (tid >= off) ? psum[tid - off] : 0;
            __syncthreads();
            psum[tid] += p;
            __syncthreads();
        }
        int run = (tid > 0) ? psum[tid - 1] : 0;
        for (int j = lo; j < hi; ++j) {
            lstart[j] = run;
            run += h[j];
        }
    }
    __syncthreads();

    // reserve global chunks (one atomic per (block,bucket))
    for (int i = tid; i < NBUCK; i += 256) {
        int c = h[i];
        int g = c ? atomicAdd(&bcursor[i], c) : 0;
        delta[i] = g - lstart[i];
    }
    __syncthreads();

    #pragma unroll
    for (int j = 0; j < EPT; ++j) {
        if (rowj[j] >= 0) {
            int e = base + j;
            int b = rowj[j] >> BSHIFT;
            int rl = rowj[j] & 255;
            int slot = lstart[b] + rk[j];
            int2 pk;
            pk.x = col[e] | (rl << 17);   // col < 2^17, rl < 2^8
            pk.y = __float_as_int(val[e]);
            stage[slot] = pk;
            bidx[slot] = (unsigned short)b;
        }
    }
    __syncthreads();

    for (int i = tid; i < m; i += 256) {
        int b = bidx[i];
        epk[delta[b] + i] = stage[i];
    }
}

// ---------------- level 2: CSR placement, column-sorted within each row ----------------
__global__ __launch_bounds__(256) void place_kernel(const int* __restrict__ bbase,
                                                    int2* __restrict__ epk,
                                                    int* __restrict__ starts,
                                                    int* __restrict__ dcnt) {
    __shared__ int kcnt[NKEY];       // 16 KB
    __shared__ int kcur[NKEY];       // 16 KB
    __shared__ int psum[256];
    __shared__ int dh[DMAX];
    __shared__ int2 stage[CAP];      // 72 KB
    int b = blockIdx.x;
    int tid = threadIdx.x;
    int gb = bbase[b];
    int n = bbase[b + 1] - gb;
    for (int j = tid; j < NKEY; j += 256) kcnt[j] = 0;
    dh[tid] = 0;
    __syncthreads();
    for (int i = tid; i < n; i += 256) {
        int x = epk[gb + i].x;
        int key = (((x >> 17) & 255) << 4) | ((x >> 13) & 15);
        atomicAdd(&kcnt[key], 1);
    }
    __syncthreads();
    // chunk=16 scan: thread tid owns exactly row tid's 16 bins
    int lo = tid << 4;
    int deg = 0;
    #pragma unroll
    for (int j = 0; j < 16; ++j) deg += kcnt[lo + j];
    int r_glob = (b << BSHIFT) + tid;
    if (r_glob < N_NODES) atomicAdd(&dh[min(deg, DMAX - 1)], 1);
    psum[tid] = deg;
    __syncthreads();
    for (int off = 1; off < 256; off <<= 1) {
        int p = (tid >= off) ? psum[tid - off] : 0;
        __syncthreads();
        psum[tid] += p;
        __syncthreads();
    }
    int run = (tid > 0) ? psum[tid - 1] : 0;
    if (r_glob < N_NODES) starts[r_glob] = gb + run;
    if (b == 0 && tid == 0) starts[N_NODES] = N_EDGES;
    #pragma unroll
    for (int j = 0; j < 16; ++j) {
        kcur[lo + j] = run;
        run += kcnt[lo + j];
    }
    __syncthreads();
    {   // flush degree histogram
        int c = dh[tid];
        if (c) atomicAdd(&dcnt[tid], c);
    }
    for (int i = tid; i < n; i += 256) {
        int2 p = epk[gb + i];
        int key = (((p.x >> 17) & 255) << 4) | ((p.x >> 13) & 15);
        int slot = atomicAdd(&kcur[key], 1);
        int2 fin;
        fin.x = p.x & 0x1FFFF;       // strip row_local
        fin.y = p.y;
        if (slot < CAP) stage[slot] = fin;
        else epk[gb + slot] = fin;   // overflow guard (statistically unreachable)
    }
    __syncthreads();
    for (int i = tid; i < n && i < CAP; i += 256) epk[gb + i] = stage[i];
}

// ---------------- degree scan + LDS-aggregated counting-sort scatter ----------------
__global__ __launch_bounds__(256) void dscan_kernel(const int* __restrict__ dcnt,
                                                    int* __restrict__ dcur) {
    __shared__ int part[DMAX];
    int tid = threadIdx.x;
    int v = dcnt[tid];
    part[tid] = v;
    __syncthreads();
    for (int off = 1; off < DMAX; off <<= 1) {
        int p = (tid >= off) ? part[tid - off] : 0;
        __syncthreads();
        part[tid] += p;
        __syncthreads();
    }
    dcur[tid] = part[tid] - v;   // exclusive
}

__global__ __launch_bounds__(256) void dscatter_kernel(const int* __restrict__ starts,
                                                       int* __restrict__ dcur,
                                                       int* __restrict__ perm) {
    __shared__ int h[DMAX];
    __shared__ int chunk[DMAX];
    int tid = threadIdx.x;
    int r = blockIdx.x * 256 + tid;
    h[tid] = 0;
    __syncthreads();
    int d = -1, rk = 0;
    if (r < N_NODES) {
        d = min(starts[r + 1] - starts[r], DMAX - 1);
        rk = atomicAdd(&h[d], 1);
    }
    __syncthreads();
    int c = h[tid];
    chunk[tid] = c ? atomicAdd(&dcur[tid], c) : 0;   // one atomic per (block,deg)
    __syncthreads();
    if (r < N_NODES) perm[chunk[d] + rk] = r;
}

// ---------------- pad-copy: x [N][24] -> bufA [N][32] ----------------
__global__ __launch_bounds__(256) void pad_copy_kernel(const float4* __restrict__ x4,
                                                       float4* __restrict__ dst) {
    int t = blockIdx.x * blockDim.x + threadIdx.x;
    int r = t >> 3;
    if (r >= N_NODES) return;
    int sub = t & 7;
    float4 v;
    if (sub < 6) v = x4[r * 6 + sub];
    else         v = make_float4(0.f, 0.f, 0.f, 0.f);
    dst[r * PADF4 + sub] = v;
}

// ---------------- SpMM: 8 lanes/row, 1 float4/lane, 4-edge unroll ----------------
// R7 residency structure (800K threads, degree-banded generations -> tight
// column window) + 4 independent gathers in flight per lane for MLP.
#define ACC4(v, xv, a)                                       \
    a.x = fmaf(v, xv.x, a.x); a.y = fmaf(v, xv.y, a.y);      \
    a.z = fmaf(v, xv.z, a.z); a.w = fmaf(v, xv.w, a.w);

__global__ __launch_bounds__(256) void spmm_pad_kernel(const int* __restrict__ starts,
                                                       const int* __restrict__ perm,
                                                       const int2* __restrict__ epk,
                                                       const float4* __restrict__ src,
                                                       float4* __restrict__ dst) {
    int t = blockIdx.x * blockDim.x + threadIdx.x;
    int g = t >> 3;
    if (g >= N_NODES) return;
    int rowi = perm[g];
    int sub = t & 7;
    int s = starts[rowi];
    int e = starts[rowi + 1];
    const float4* sp = src + sub;
    float4 acc = make_float4(0.f, 0.f, 0.f, 0.f);
    int i = s;
    for (; i + 3 < e; i += 4) {
        int2 p0 = epk[i];
        int2 p1 = epk[i + 1];
        int2 p2 = epk[i + 2];
        int2 p3 = epk[i + 3];
        float4 x0 = sp[p0.x * PADF4];
        float4 x1 = sp[p1.x * PADF4];
        float4 x2 = sp[p2.x * PADF4];
        float4 x3 = sp[p3.x * PADF4];
        float v0 = __int_as_float(p0.y);
        float v1 = __int_as_float(p1.y);
        float v2 = __int_as_float(p2.y);
        float v3 = __int_as_float(p3.y);
        ACC4(v0, x0, acc);
        ACC4(v1, x1, acc);
        ACC4(v2, x2, acc);
        ACC4(v3, x3, acc);
    }
    for (; i < e; ++i) {
        int2 p = epk[i];
        float4 xv = sp[p.x * PADF4];
        float v = __int_as_float(p.y);
        ACC4(v, xv, acc);
    }
    dst[rowi * PADF4 + sub] = acc;
}

__global__ __launch_bounds__(256) void spmm_final_kernel(const int* __restrict__ starts,
                                                         const int* __restrict__ perm,
                                                         const int2* __restrict__ epk,
                                                         const float4* __restrict__ src,
                                                         float* __restrict__ out) {
    int t = blockIdx.x * blockDim.x + threadIdx.x;
    int g = t >> 3;
    if (g >= N_NODES) return;
    int rowi = perm[g];
    int sub = t & 7;
    int s = starts[rowi];
    int e = starts[rowi + 1];
    const float4* sp = src + sub;
    float4 acc = make_float4(0.f, 0.f, 0.f, 0.f);
    int i = s;
    for (; i + 3 < e; i += 4) {
        int2 p0 = epk[i];
        int2 p1 = epk[i + 1];
        int2 p2 = epk[i + 2];
        int2 p3 = epk[i + 3];
        float4 x0 = sp[p0.x * PADF4];
        float4 x1 = sp[p1.x * PADF4];
        float4 x2 = sp[p2.x * PADF4];
        float4 x3 = sp[p3.x * PADF4];
        float v0 = __int_as_float(p0.y);
        float v1 = __int_as_float(p1.y);
        float v2 = __int_as_float(p2.y);
        float v3 = __int_as_float(p3.y);
        ACC4(v0, x0, acc);
        ACC4(v1, x1, acc);
        ACC4(v2, x2, acc);
        ACC4(v3, x3, acc);
    }
    for (; i < e; ++i) {
        int2 p = epk[i];
        float4 xv = sp[p.x * PADF4];
        float v = __int_as_float(p.y);
        ACC4(v, xv, acc);
    }
    if (sub < 6) *(float4*)(out + rowi * N_FEAT + sub * 4) = acc;
}

// ---------------- launch ----------------

extern "C" void kernel_launch(void* const* d_in, const int* in_sizes, int n_in,
                              void* d_out, int out_size, void* d_ws, size_t ws_size,
                              hipStream_t stream) {
    const float* x       = (const float*)d_in[0];
    const float* values  = (const float*)d_in[1];
    const int*   row_idx = (const int*)d_in[2];
    const int*   col_idx = (const int*)d_in[3];
    float* out = (float*)d_out;

    char* ws = (char*)d_ws;
    // workspace layout (~52MB, 128B-aligned offsets)
    int*    bcnt    = (int*)(ws + 0);          // NBUCK ints
    int*    bbase   = (int*)(ws + 2048);       // NBUCK+1 ints
    int*    bcursor = (int*)(ws + 4096);       // NBUCK ints
    int*    dcnt    = (int*)(ws + 6144);       // DMAX ints
    int*    dcur    = (int*)(ws + 7168);       // DMAX ints
    int*    starts  = (int*)(ws + 8192);       // N_NODES+1 ints
    int*    perm    = (int*)(ws + 408576);     // N_NODES ints
    int2*   epk     = (int2*)(ws + 808576);    // E * 8B = 25.6 MB
    float4* bufA    = (float4*)(ws + 26408576);// N*32 floats = 12.8 MB
    float4* bufB    = (float4*)(ws + 39208576);// N*32 floats = 12.8 MB

    zero_kernel<<<4, 256, 0, stream>>>(bcnt, NBUCK);
    zero_kernel<<<1, 256, 0, stream>>>(dcnt, DMAX);
    bhist_kernel<<<512, 256, 0, stream>>>(row_idx, bcnt);
    bscan_kernel<<<1, 512, 0, stream>>>(bcnt, bbase, bcursor);
    part_kernel<<<NTILES, 256, 0, stream>>>(row_idx, col_idx, values, bcursor, epk);
    place_kernel<<<NBUCK, 256, 0, stream>>>(bbase, epk, starts, dcnt);

    const int node_blocks = (N_NODES + 255) / 256;
    dscan_kernel<<<1, DMAX, 0, stream>>>(dcnt, dcur);
    dscatter_kernel<<<node_blocks, 256, 0, stream>>>(starts, dcur, perm);

    const int spmm_blocks = (N_NODES * 8 + 255) / 256;
    pad_copy_kernel<<<spmm_blocks, 256, 0, stream>>>((const float4*)x, bufA);
    spmm_pad_kernel<<<spmm_blocks, 256, 0, stream>>>(starts, perm, epk, bufA, bufB);
    spmm_pad_kernel<<<spmm_blocks, 256, 0, stream>>>(starts, perm, epk, bufB, bufA);
    spmm_pad_kernel<<<spmm_blocks, 256, 0, stream>>>(starts, perm, epk, bufA, bufB);
    spmm_pad_kernel<<<spmm_blocks, 256, 0, stream>>>(starts, perm, epk, bufB, bufA);
    spmm_pad_kernel<<<spmm_blocks, 256, 0, stream>>>(starts, perm, epk, bufA, bufB);
    spmm_final_kernel<<<spmm_blocks, 256, 0, stream>>>(starts, perm, epk, bufB, out);
}